// Round 6
// baseline (361.558 us; speedup 1.0000x reference)
//
#include <hip/hip_runtime.h>
#include <math.h>

#define B_  4
#define S_  2048
#define D_  1024
#define H_  16
#define HD_ 64
#define M_  (B_*S_)   // 8192

typedef short short8 __attribute__((ext_vector_type(8)));
typedef float f32x4 __attribute__((ext_vector_type(4)));

#define MFMA16(a,b,c) __builtin_amdgcn_mfma_f32_16x16x32_bf16(a, b, c, 0, 0, 0)

#if __has_builtin(__builtin_amdgcn_exp2f)
#define EXP2(x) __builtin_amdgcn_exp2f(x)
#else
#define EXP2(x) exp2f(x)
#endif

__device__ __forceinline__ unsigned short f2bf(float f) {
    unsigned u = __float_as_uint(f);
    u = (u + 0x7FFF + ((u >> 16) & 1)) >> 16;
    return (unsigned short)u;
}

// pack two fp32 -> two bf16 in one u32 (RNE)
__device__ __forceinline__ unsigned pack_bf16(float a, float b) {
#if __has_builtin(__builtin_amdgcn_cvt_pk_bf16_f32)
    typedef __bf16 bf2 __attribute__((ext_vector_type(2)));
    bf2 v = __builtin_amdgcn_cvt_pk_bf16_f32(a, b);
    unsigned r;
    __builtin_memcpy(&r, &v, 4);
    return r;
#else
    unsigned ua = __float_as_uint(a), ub = __float_as_uint(b);
    ua += 0x7FFFu + ((ua >> 16) & 1u);
    ub += 0x7FFFu + ((ub >> 16) & 1u);
    return __builtin_amdgcn_perm(ub, ua, 0x07060302u);
#endif
}

__device__ __forceinline__ void async_copy16(const void* g, void* l) {
    __builtin_amdgcn_global_load_lds(
        (const __attribute__((address_space(1))) void*)g,
        (__attribute__((address_space(3))) void*)l, 16, 0, 0);
}

// ---------------- fused fp32->bf16 conversion (x + 4 weights) ----------------
__global__ __launch_bounds__(256) void cvt_all(
    const float* __restrict__ x,
    const float* __restrict__ w0, const float* __restrict__ w1,
    const float* __restrict__ w2, const float* __restrict__ w3,
    unsigned short* __restrict__ xb, unsigned short* __restrict__ wb)
{
    size_t i = ((size_t)blockIdx.x * 256 + threadIdx.x) * 4;
    const float* src; unsigned short* dst;
    if (i < (size_t)M_ * D_) {
        src = x + i; dst = xb + i;
    } else {
        size_t j = i - (size_t)M_ * D_;
        int z = (int)(j >> 20);               // D_*D_ = 2^20
        const float* w = (z == 0) ? w0 : (z == 1) ? w1 : (z == 2) ? w2 : w3;
        src = w + (j & ((size_t)D_ * D_ - 1)); dst = wb + j;
    }
    float4 v = *(const float4*)src;
    uint2 o;
    o.x = pack_bf16(v.x, v.y);
    o.y = pack_bf16(v.z, v.w);
    *(uint2*)dst = o;
}

// ---------------- bf16 MFMA GEMM, BK=64, swizzled LDS ----------------
__device__ __forceinline__ void gemm_body(
    const unsigned short* __restrict__ A, const unsigned short* __restrict__ W,
    const float* __restrict__ bias, void* __restrict__ out,
    int mode, float cscale, int bx, int by)
{
    __shared__ unsigned short As[128 * 64];
    __shared__ unsigned short Ws[128 * 64];
    const int K = D_;
    int tid = threadIdx.x;
    int w = tid >> 6, lane = tid & 63;
    int quad = lane >> 4, l16 = lane & 15;
    int r8 = lane >> 3, c8 = lane & 7;
    int cK = c8 ^ r8;
    int wm = w >> 1, wn = w & 1;
    int m0 = by * 128, n0 = bx * 128;
    int fl = l16 & 7;

    f32x4 acc[4][4];
    #pragma unroll
    for (int i = 0; i < 4; ++i)
        #pragma unroll
        for (int j = 0; j < 4; ++j)
            acc[i][j] = (f32x4){0.f, 0.f, 0.f, 0.f};

    const unsigned short* Ag = A + (size_t)(m0 + w * 32 + r8) * K + cK * 8;
    const unsigned short* Wg = W + (size_t)(n0 + w * 32 + r8) * K + cK * 8;

    for (int k0 = 0; k0 < K; k0 += 64) {
        __syncthreads();
        #pragma unroll
        for (int ii = 0; ii < 4; ++ii) {
            async_copy16(Ag + k0 + (size_t)ii * 8 * K, As + (w * 32 + ii * 8) * 64);
            async_copy16(Wg + k0 + (size_t)ii * 8 * K, Ws + (w * 32 + ii * 8) * 64);
        }
        __syncthreads();
        #pragma unroll
        for (int s = 0; s < 2; ++s) {
            int st = ((quad + s * 4) ^ fl) * 8;
            short8 a[4], b[4];
            #pragma unroll
            for (int i = 0; i < 4; ++i)
                a[i] = *(const short8*)&As[(wm * 64 + i * 16 + l16) * 64 + st];
            #pragma unroll
            for (int j = 0; j < 4; ++j)
                b[j] = *(const short8*)&Ws[(wn * 64 + j * 16 + l16) * 64 + st];
            #pragma unroll
            for (int i = 0; i < 4; ++i)
                #pragma unroll
                for (int j = 0; j < 4; ++j)
                    acc[i][j] = MFMA16(a[i], b[j], acc[i][j]);
        }
    }

    #pragma unroll
    for (int i = 0; i < 4; ++i) {
        int mb = m0 + wm * 64 + i * 16 + quad * 4;
        #pragma unroll
        for (int j = 0; j < 4; ++j) {
            int n = n0 + wn * 64 + j * 16 + l16;
            float bn = bias[n];
            if (mode == 0) {
                #pragma unroll
                for (int r = 0; r < 4; ++r)
                    ((float*)out)[(size_t)(mb + r) * D_ + n] = acc[i][j][r] + bn;
            } else if (mode == 1) {
                int h = n >> 6, hd = n & 63;
                #pragma unroll
                for (int r = 0; r < 4; ++r) {
                    int m = mb + r;
                    int bb = m >> 11, s = m & (S_ - 1);
                    ((unsigned short*)out)[(((size_t)(bb * H_ + h)) * S_ + s) * HD_ + hd] =
                        f2bf((acc[i][j][r] + bn) * cscale);
                }
            } else {
                int h = n >> 6, hd = n & 63;
                int bb = mb >> 11, s0 = mb & (S_ - 1);
                uint2 o;
                o.x = pack_bf16(acc[i][j][0] + bn, acc[i][j][1] + bn);
                o.y = pack_bf16(acc[i][j][2] + bn, acc[i][j][3] + bn);
                *(uint2*)&((unsigned short*)out)[(((size_t)(bb * H_ + h)) * HD_ + hd) * S_ + s0] = o;
            }
        }
    }
}

__global__ __launch_bounds__(256) void qkv_gemm(
    const unsigned short* __restrict__ A,
    const unsigned short* __restrict__ Wq, const unsigned short* __restrict__ Wk,
    const unsigned short* __restrict__ Wv,
    const float* __restrict__ bq, const float* __restrict__ bk, const float* __restrict__ bv,
    unsigned short* Qo, unsigned short* Ko, unsigned short* Vo)
{
    int z = blockIdx.z;
    const unsigned short* W = (z == 0) ? Wq : (z == 1) ? Wk : Wv;
    const float* bias = (z == 0) ? bq : (z == 1) ? bk : bv;
    unsigned short* out = (z == 0) ? Qo : (z == 1) ? Ko : Vo;
    // Q pre-scaled by 1/sqrt(64) * log2(e) so softmax uses exp2 directly
    float cscale = (z == 0) ? 0.125f * 1.44269504088896f : 1.0f;
    int mode = (z == 2) ? 2 : 1;
    gemm_body(A, W, bias, out, mode, cscale, blockIdx.x, blockIdx.y);
}

__global__ __launch_bounds__(256) void out_gemm(
    const unsigned short* __restrict__ A, const unsigned short* __restrict__ W,
    const float* __restrict__ bias, float* __restrict__ out)
{
    gemm_body(A, W, bias, out, 0, 1.0f, blockIdx.x, blockIdx.y);
}

// ---------------- flash attention v5: register-prefetch pipelined K/V -------
// Block = 128 queries of one (b,h); 4 waves x 32 queries.
// K/V tile kt+1 is loaded into registers while tile kt computes; consumed as
// swizzled ds_write_b128 at the top of the next iteration. Both barriers are
// cheap: the end-barrier's vmcnt(0) drain hits loads that had the whole
// compute phase to fly. LDS stays 32 KB (5-block/CU cap, no tail).
__global__ __launch_bounds__(256) void attn_mfma(
    const unsigned short* __restrict__ Q, const unsigned short* __restrict__ K,
    const unsigned short* __restrict__ VT, unsigned short* __restrict__ ctx)
{
    __shared__ unsigned short Ks[64 * 64];
    __shared__ unsigned short VTs[64 * 64];
    __shared__ unsigned short QPs[128 * 64];   // Q staged, then P (wave-private rows)

    int tid = threadIdx.x;
    int w = tid >> 6, lane = tid & 63;
    int quad = lane >> 4, l16 = lane & 15;
    int r8 = lane >> 3, c8 = lane & 7;
    int fl  = l16 & 7;                    // K/V read key
    int fl2 = (l16 ^ (l16 >> 1)) & 7;     // Q/P swizzle key
    int bh = blockIdx.y;
    int q0 = blockIdx.x * 128;

    const unsigned short* Qp = Q + ((size_t)bh * S_ + q0) * HD_;
    const unsigned short* Kp = K + (size_t)bh * S_ * HD_;
    const unsigned short* Vp = VT + (size_t)bh * HD_ * S_;

    // stage Q tile [128][64] with f2 swizzle (one-time async)
    #pragma unroll
    for (int ii = 0; ii < 4; ++ii) {
        int cQ = c8 ^ r8 ^ (r8 >> 1) ^ ((ii & 1) * 4);
        async_copy16(Qp + (size_t)(w * 32 + ii * 8 + r8) * HD_ + cQ * 8,
                     QPs + (w * 32 + ii * 8) * 64);
    }

    // register prefetch buffers: this wave stages tile rows rb0..rb0+15
    int rb0 = w * 16;
    uint4 kbuf[2], vbuf[2];
    #pragma unroll
    for (int ii = 0; ii < 2; ++ii) {
        kbuf[ii] = *(const uint4*)(Kp + (size_t)(rb0 + ii * 8 + r8) * HD_ + c8 * 8);
        vbuf[ii] = *(const uint4*)(Vp + (size_t)(rb0 + ii * 8 + r8) * S_ + c8 * 8);
    }

    __syncthreads();   // Q async drained (vmcnt 0)

    // Q fragments (B-operand: n=query=l16, k=quad*8+j)
    short8 bq_[2][2];
    #pragma unroll
    for (int mt = 0; mt < 2; ++mt)
        #pragma unroll
        for (int s = 0; s < 2; ++s)
            bq_[mt][s] = *(const short8*)&QPs[(w * 32 + mt * 16 + l16) * 64 +
                                              (((quad + s * 4) ^ fl2) * 8)];

    f32x4 O[2][4];
    float lsum[2] = {0.f, 0.f};
    #pragma unroll
    for (int mt = 0; mt < 2; ++mt)
        #pragma unroll
        for (int nt = 0; nt < 4; ++nt) O[mt][nt] = (f32x4){0.f, 0.f, 0.f, 0.f};

    for (int kt = 0; kt < S_ / 64; ++kt) {
        // regs(kt) -> LDS, swizzled: chunk c8 of row r at chunk c8^r8
        #pragma unroll
        for (int ii = 0; ii < 2; ++ii) {
            *(uint4*)&Ks[(rb0 + ii * 8 + r8) * 64 + (c8 ^ r8) * 8] = kbuf[ii];
            *(uint4*)&VTs[(rb0 + ii * 8 + r8) * 64 + (c8 ^ r8) * 8] = vbuf[ii];
        }
        __syncthreads();           // writes visible; nothing in vmem flight

        // issue prefetch of tile kt+1 (hidden under this iteration's compute)
        if (kt + 1 < S_ / 64) {
            #pragma unroll
            for (int ii = 0; ii < 2; ++ii) {
                kbuf[ii] = *(const uint4*)(Kp + (size_t)((kt + 1) * 64 + rb0 + ii * 8 + r8) * HD_ + c8 * 8);
                vbuf[ii] = *(const uint4*)(Vp + (size_t)(rb0 + ii * 8 + r8) * S_ + (kt + 1) * 64 + c8 * 8);
            }
        }

        // S^T = K @ Q^T: sc[mt][nt] has col=query(l16), rows=keys(quad*4+r)
        f32x4 sc[2][4];
        #pragma unroll
        for (int mt = 0; mt < 2; ++mt)
            #pragma unroll
            for (int nt = 0; nt < 4; ++nt) sc[mt][nt] = (f32x4){0.f, 0.f, 0.f, 0.f};
        #pragma unroll
        for (int s = 0; s < 2; ++s) {
            int stk = ((quad + s * 4) ^ fl) * 8;
            #pragma unroll
            for (int nt = 0; nt < 4; ++nt) {
                short8 ak = *(const short8*)&Ks[(nt * 16 + l16) * 64 + stk];
                sc[0][nt] = MFMA16(ak, bq_[0][s], sc[0][nt]);
                sc[1][nt] = MFMA16(ak, bq_[1][s], sc[1][nt]);
            }
        }

        // p = exp2(s); packed-pair bf16; scalar tree row-sums
        #pragma unroll
        for (int mt = 0; mt < 2; ++mt) {
            #pragma unroll
            for (int nt = 0; nt < 4; ++nt) {
                float p0 = EXP2(sc[mt][nt][0]);
                float p1 = EXP2(sc[mt][nt][1]);
                float p2 = EXP2(sc[mt][nt][2]);
                float p3 = EXP2(sc[mt][nt][3]);
                lsum[mt] += (p0 + p1) + (p2 + p3);
                uint2 pk;
                pk.x = pack_bf16(p0, p1);
                pk.y = pack_bf16(p2, p3);
                // row = query, col = key = nt*16 + quad*4 + r
                int addr = (w * 32 + mt * 16 + l16) * 64 +
                           (((nt * 2 + (quad >> 1)) ^ fl2) * 8) + (quad & 1) * 4;
                *(uint2*)&QPs[addr] = pk;
            }
        }

        // O += P @ V  (wave-local LDS round trip)
        #pragma unroll
        for (int s = 0; s < 2; ++s) {
            int stp = ((quad + s * 4) ^ fl2) * 8;
            int stv = ((quad + s * 4) ^ fl) * 8;
            short8 pa0 = *(const short8*)&QPs[(w * 32 + l16) * 64 + stp];
            short8 pa1 = *(const short8*)&QPs[(w * 32 + 16 + l16) * 64 + stp];
            #pragma unroll
            for (int nt = 0; nt < 4; ++nt) {
                short8 bv_ = *(const short8*)&VTs[(nt * 16 + l16) * 64 + stv];
                O[0][nt] = MFMA16(pa0, bv_, O[0][nt]);
                O[1][nt] = MFMA16(pa1, bv_, O[1][nt]);
            }
        }

        __syncthreads();   // all reads done before next store_tile overwrites;
                           // drains prefetch (already ~complete under compute)
    }

    // row sums: reduce over quad lanes (each lane holds 16 of its query's keys)
    float linv[2];
    #pragma unroll
    for (int mt = 0; mt < 2; ++mt) {
        float l = lsum[mt];
        l += __shfl_xor(l, 16);
        l += __shfl_xor(l, 32);
        linv[mt] = 1.0f / l;      // sum for query (w*32 + mt*16 + l16)
    }

    // normalize + write: O rows are queries quad*4+r -> fetch inv via shuffle
    int b = bh >> 4, h = bh & (H_ - 1);
    #pragma unroll
    for (int mt = 0; mt < 2; ++mt)
        #pragma unroll
        for (int r = 0; r < 4; ++r) {
            float inv = __shfl(linv[mt], quad * 4 + r, 64);
            int q = q0 + w * 32 + mt * 16 + quad * 4 + r;
            size_t base = ((size_t)(b * S_) + q) * D_ + h * HD_;
            #pragma unroll
            for (int nt = 0; nt < 4; ++nt)
                ctx[base + nt * 16 + l16] = f2bf(O[mt][nt][r] * inv);
        }
}

extern "C" void kernel_launch(void* const* d_in, const int* in_sizes, int n_in,
                              void* d_out, int out_size, void* d_ws, size_t ws_size,
                              hipStream_t stream) {
    const float* x  = (const float*)d_in[0];
    const float* Wq = (const float*)d_in[1];
    const float* bq = (const float*)d_in[2];
    const float* Wk = (const float*)d_in[3];
    const float* bk = (const float*)d_in[4];
    const float* Wv = (const float*)d_in[5];
    const float* bv = (const float*)d_in[6];
    const float* Wo = (const float*)d_in[7];
    const float* bo = (const float*)d_in[8];

    unsigned short* xb  = (unsigned short*)d_ws;
    unsigned short* wb  = xb + (size_t)M_ * D_;
    unsigned short* Qb  = wb + (size_t)4 * D_ * D_;
    unsigned short* Kb  = Qb + (size_t)M_ * D_;
    unsigned short* VTb = Kb + (size_t)M_ * D_;
    unsigned short* ctb = VTb + (size_t)M_ * D_;

    int cvt_blocks = (M_ * D_ + 4 * D_ * D_) / 1024;
    cvt_all<<<cvt_blocks, 256, 0, stream>>>(x, Wq, Wk, Wv, Wo, xb, wb);

    qkv_gemm<<<dim3(D_ / 128, M_ / 128, 3), 256, 0, stream>>>(
        xb, wb, wb + (size_t)D_ * D_, wb + (size_t)2 * D_ * D_,
        bq, bk, bv, Qb, Kb, VTb);

    attn_mfma<<<dim3(S_ / 128, B_ * H_), 256, 0, stream>>>(Qb, Kb, VTb, ctb);

    out_gemm<<<dim3(D_ / 128, M_ / 128), 256, 0, stream>>>(
        ctb, wb + (size_t)3 * D_ * D_, bo, (float*)d_out);
}

// Round 7
// 303.337 us; speedup vs baseline: 1.1919x; 1.1919x over previous
//
#include <hip/hip_runtime.h>
#include <math.h>

#define B_  4
#define S_  2048
#define D_  1024
#define H_  16
#define HD_ 64
#define M_  (B_*S_)   // 8192

typedef short short8 __attribute__((ext_vector_type(8)));
typedef float f32x4 __attribute__((ext_vector_type(4)));

#define MFMA16(a,b,c) __builtin_amdgcn_mfma_f32_16x16x32_bf16(a, b, c, 0, 0, 0)

#if __has_builtin(__builtin_amdgcn_exp2f)
#define EXP2(x) __builtin_amdgcn_exp2f(x)
#else
#define EXP2(x) exp2f(x)
#endif

__device__ __forceinline__ unsigned short f2bf(float f) {
    unsigned u = __float_as_uint(f);
    u = (u + 0x7FFF + ((u >> 16) & 1)) >> 16;
    return (unsigned short)u;
}

// pack two fp32 -> two bf16 in one u32 (RNE)
__device__ __forceinline__ unsigned pack_bf16(float a, float b) {
#if __has_builtin(__builtin_amdgcn_cvt_pk_bf16_f32)
    typedef __bf16 bf2 __attribute__((ext_vector_type(2)));
    bf2 v = __builtin_amdgcn_cvt_pk_bf16_f32(a, b);
    unsigned r;
    __builtin_memcpy(&r, &v, 4);
    return r;
#else
    unsigned ua = __float_as_uint(a), ub = __float_as_uint(b);
    ua += 0x7FFFu + ((ua >> 16) & 1u);
    ub += 0x7FFFu + ((ub >> 16) & 1u);
    return __builtin_amdgcn_perm(ub, ua, 0x07060302u);
#endif
}

__device__ __forceinline__ void async_copy16(const void* g, void* l) {
    __builtin_amdgcn_global_load_lds(
        (const __attribute__((address_space(1))) void*)g,
        (__attribute__((address_space(3))) void*)l, 16, 0, 0);
}

// ---------------- fused fp32->bf16 conversion (x + 4 weights) ----------------
__global__ __launch_bounds__(256) void cvt_all(
    const float* __restrict__ x,
    const float* __restrict__ w0, const float* __restrict__ w1,
    const float* __restrict__ w2, const float* __restrict__ w3,
    unsigned short* __restrict__ xb, unsigned short* __restrict__ wb)
{
    size_t i = ((size_t)blockIdx.x * 256 + threadIdx.x) * 4;
    const float* src; unsigned short* dst;
    if (i < (size_t)M_ * D_) {
        src = x + i; dst = xb + i;
    } else {
        size_t j = i - (size_t)M_ * D_;
        int z = (int)(j >> 20);               // D_*D_ = 2^20
        const float* w = (z == 0) ? w0 : (z == 1) ? w1 : (z == 2) ? w2 : w3;
        src = w + (j & ((size_t)D_ * D_ - 1)); dst = wb + j;
    }
    float4 v = *(const float4*)src;
    uint2 o;
    o.x = pack_bf16(v.x, v.y);
    o.y = pack_bf16(v.z, v.w);
    *(uint2*)dst = o;
}

// ---------------- bf16 MFMA GEMM, 512 threads, BK=64, swizzled LDS ----------
// 128x128 tile, 8 waves as 2x4 (wm: 64-row half, wn: 32-col quarter).
// acc 32 VGPR/wave -> ~70 total: 3 blocks x 8 waves = 24 waves/CU; the qkv
// grid (1536 blocks) becomes exactly 2 clean scheduling cohorts of 768.
__device__ __forceinline__ void gemm_body(
    const unsigned short* __restrict__ A, const unsigned short* __restrict__ W,
    const float* __restrict__ bias, void* __restrict__ out,
    int mode, float cscale, int bx, int by)
{
    __shared__ unsigned short As[128 * 64];
    __shared__ unsigned short Ws[128 * 64];
    const int K = D_;
    int tid = threadIdx.x;
    int w = tid >> 6, lane = tid & 63;
    int quad = lane >> 4, l16 = lane & 15;
    int r8 = lane >> 3, c8 = lane & 7;
    int cK = c8 ^ r8;                       // staged source chunk (row&7 = r8)
    int wm = w >> 2, wn = w & 3;
    int m0 = by * 128, n0 = bx * 128;
    int fl = l16 & 7;

    f32x4 acc[4][2];
    #pragma unroll
    for (int i = 0; i < 4; ++i)
        #pragma unroll
        for (int j = 0; j < 2; ++j)
            acc[i][j] = (f32x4){0.f, 0.f, 0.f, 0.f};

    // wave w stages rows (ii*64 + w*8 + r8), chunk cK
    const unsigned short* Ag = A + (size_t)(m0 + w * 8 + r8) * K + cK * 8;
    const unsigned short* Wg = W + (size_t)(n0 + w * 8 + r8) * K + cK * 8;

    for (int k0 = 0; k0 < K; k0 += 64) {
        __syncthreads();
        #pragma unroll
        for (int ii = 0; ii < 2; ++ii) {
            async_copy16(Ag + k0 + (size_t)ii * 64 * K, As + (ii * 64 + w * 8) * 64);
            async_copy16(Wg + k0 + (size_t)ii * 64 * K, Ws + (ii * 64 + w * 8) * 64);
        }
        __syncthreads();
        #pragma unroll
        for (int s = 0; s < 2; ++s) {
            int st = ((quad + s * 4) ^ fl) * 8;
            short8 a[4], b[2];
            #pragma unroll
            for (int i = 0; i < 4; ++i)
                a[i] = *(const short8*)&As[(wm * 64 + i * 16 + l16) * 64 + st];
            #pragma unroll
            for (int j = 0; j < 2; ++j)
                b[j] = *(const short8*)&Ws[(wn * 32 + j * 16 + l16) * 64 + st];
            #pragma unroll
            for (int i = 0; i < 4; ++i)
                #pragma unroll
                for (int j = 0; j < 2; ++j)
                    acc[i][j] = MFMA16(a[i], b[j], acc[i][j]);
        }
    }

    #pragma unroll
    for (int i = 0; i < 4; ++i) {
        int mb = m0 + wm * 64 + i * 16 + quad * 4;
        #pragma unroll
        for (int j = 0; j < 2; ++j) {
            int n = n0 + wn * 32 + j * 16 + l16;
            float bn = bias[n];
            if (mode == 0) {
                #pragma unroll
                for (int r = 0; r < 4; ++r)
                    ((float*)out)[(size_t)(mb + r) * D_ + n] = acc[i][j][r] + bn;
            } else if (mode == 1) {
                int h = n >> 6, hd = n & 63;
                #pragma unroll
                for (int r = 0; r < 4; ++r) {
                    int m = mb + r;
                    int bb = m >> 11, s = m & (S_ - 1);
                    ((unsigned short*)out)[(((size_t)(bb * H_ + h)) * S_ + s) * HD_ + hd] =
                        f2bf((acc[i][j][r] + bn) * cscale);
                }
            } else {
                int h = n >> 6, hd = n & 63;
                int bb = mb >> 11, s0 = mb & (S_ - 1);
                uint2 o;
                o.x = pack_bf16(acc[i][j][0] + bn, acc[i][j][1] + bn);
                o.y = pack_bf16(acc[i][j][2] + bn, acc[i][j][3] + bn);
                *(uint2*)&((unsigned short*)out)[(((size_t)(bb * H_ + h)) * HD_ + hd) * S_ + s0] = o;
            }
        }
    }
}

__global__ __launch_bounds__(512) void qkv_gemm(
    const unsigned short* __restrict__ A,
    const unsigned short* __restrict__ Wq, const unsigned short* __restrict__ Wk,
    const unsigned short* __restrict__ Wv,
    const float* __restrict__ bq, const float* __restrict__ bk, const float* __restrict__ bv,
    unsigned short* Qo, unsigned short* Ko, unsigned short* Vo)
{
    int z = blockIdx.z;
    const unsigned short* W = (z == 0) ? Wq : (z == 1) ? Wk : Wv;
    const float* bias = (z == 0) ? bq : (z == 1) ? bk : bv;
    unsigned short* out = (z == 0) ? Qo : (z == 1) ? Ko : Vo;
    // Q pre-scaled by 1/sqrt(64) * log2(e) so softmax uses exp2 directly
    float cscale = (z == 0) ? 0.125f * 1.44269504088896f : 1.0f;
    int mode = (z == 2) ? 2 : 1;
    gemm_body(A, W, bias, out, mode, cscale, blockIdx.x, blockIdx.y);
}

__global__ __launch_bounds__(512) void out_gemm(
    const unsigned short* __restrict__ A, const unsigned short* __restrict__ W,
    const float* __restrict__ bias, float* __restrict__ out)
{
    gemm_body(A, W, bias, out, 0, 1.0f, blockIdx.x, blockIdx.y);
}

// ---------------- flash attention (R4-best: 123 us, VGPR 64) ----------------
// Block = 128 queries of one (b,h); 4 waves x 32 queries.
// Score MFMA computes S^T (A = K-frag, B = Q-frag) so each lane's 4 C-regs are
// 4 CONSECUTIVE KEYS of one query -> P written as ushort4 (ds_write_b64).
// Max-free streaming softmax via exp2 (log2e folded into Q projection).
__global__ __launch_bounds__(256) void attn_mfma(
    const unsigned short* __restrict__ Q, const unsigned short* __restrict__ K,
    const unsigned short* __restrict__ VT, unsigned short* __restrict__ ctx)
{
    __shared__ unsigned short Ks[64 * 64];
    __shared__ unsigned short VTs[64 * 64];
    __shared__ unsigned short QPs[128 * 64];   // Q staged, then P (wave-private rows)

    int tid = threadIdx.x;
    int w = tid >> 6, lane = tid & 63;
    int quad = lane >> 4, l16 = lane & 15;
    int r8 = lane >> 3, c8 = lane & 7;
    int cK = c8 ^ r8;                     // K/V staging swizzle f(r)=r&7
    int fl  = l16 & 7;                    // K/V read key
    int fl2 = (l16 ^ (l16 >> 1)) & 7;     // Q/P swizzle key
    int bh = blockIdx.y;
    int q0 = blockIdx.x * 128;

    const unsigned short* Qp = Q + ((size_t)bh * S_ + q0) * HD_;
    const unsigned short* Kp = K + (size_t)bh * S_ * HD_;
    const unsigned short* Vp = VT + (size_t)bh * HD_ * S_;

    // stage Q tile [128][64] with f2 swizzle
    #pragma unroll
    for (int ii = 0; ii < 4; ++ii) {
        int cQ = c8 ^ r8 ^ (r8 >> 1) ^ ((ii & 1) * 4);
        async_copy16(Qp + (size_t)(w * 32 + ii * 8 + r8) * HD_ + cQ * 8,
                     QPs + (w * 32 + ii * 8) * 64);
    }
    __syncthreads();

    // Q fragments (B-operand: n=query=l16, k=quad*8+j)
    short8 bq_[2][2];
    #pragma unroll
    for (int mt = 0; mt < 2; ++mt)
        #pragma unroll
        for (int s = 0; s < 2; ++s)
            bq_[mt][s] = *(const short8*)&QPs[(w * 32 + mt * 16 + l16) * 64 +
                                              (((quad + s * 4) ^ fl2) * 8)];

    f32x4 O[2][4];
    float lsum[2] = {0.f, 0.f};
    #pragma unroll
    for (int mt = 0; mt < 2; ++mt)
        #pragma unroll
        for (int nt = 0; nt < 4; ++nt) O[mt][nt] = (f32x4){0.f, 0.f, 0.f, 0.f};

    for (int kt = 0; kt < S_ / 64; ++kt) {
        __syncthreads();
        #pragma unroll
        for (int ih = 0; ih < 2; ++ih) {
            int rb = w * 16 + ih * 8;
            async_copy16(Kp + (size_t)(kt * 64 + rb + r8) * HD_ + cK * 8, Ks + rb * 64);
            async_copy16(Vp + (size_t)(rb + r8) * S_ + kt * 64 + cK * 8, VTs + rb * 64);
        }
        __syncthreads();

        // S^T = K @ Q^T: sc[mt][nt] has col=query(l16), rows=keys(quad*4+r)
        f32x4 sc[2][4];
        #pragma unroll
        for (int mt = 0; mt < 2; ++mt)
            #pragma unroll
            for (int nt = 0; nt < 4; ++nt) sc[mt][nt] = (f32x4){0.f, 0.f, 0.f, 0.f};
        #pragma unroll
        for (int s = 0; s < 2; ++s) {
            int stk = ((quad + s * 4) ^ fl) * 8;
            #pragma unroll
            for (int nt = 0; nt < 4; ++nt) {
                short8 ak = *(const short8*)&Ks[(nt * 16 + l16) * 64 + stk];
                sc[0][nt] = MFMA16(ak, bq_[0][s], sc[0][nt]);
                sc[1][nt] = MFMA16(ak, bq_[1][s], sc[1][nt]);
            }
        }

        // p = exp2(s) (Q pre-scaled by log2e/8); packed ushort4 P-writes
        #pragma unroll
        for (int mt = 0; mt < 2; ++mt) {
            #pragma unroll
            for (int nt = 0; nt < 4; ++nt) {
                float p0 = EXP2(sc[mt][nt][0]);
                float p1 = EXP2(sc[mt][nt][1]);
                float p2 = EXP2(sc[mt][nt][2]);
                float p3 = EXP2(sc[mt][nt][3]);
                lsum[mt] += (p0 + p1) + (p2 + p3);
                ushort4 pk;
                pk.x = f2bf(p0); pk.y = f2bf(p1); pk.z = f2bf(p2); pk.w = f2bf(p3);
                // row = query, col = key = nt*16 + quad*4 + r
                int addr = (w * 32 + mt * 16 + l16) * 64 +
                           (((nt * 2 + (quad >> 1)) ^ fl2) * 8) + (quad & 1) * 4;
                *(ushort4*)&QPs[addr] = pk;
            }
        }

        // O += P @ V  (wave-local LDS round trip)
        #pragma unroll
        for (int s = 0; s < 2; ++s) {
            int stp = ((quad + s * 4) ^ fl2) * 8;
            int stv = ((quad + s * 4) ^ fl) * 8;
            short8 pa0 = *(const short8*)&QPs[(w * 32 + l16) * 64 + stp];
            short8 pa1 = *(const short8*)&QPs[(w * 32 + 16 + l16) * 64 + stp];
            #pragma unroll
            for (int nt = 0; nt < 4; ++nt) {
                short8 bv_ = *(const short8*)&VTs[(nt * 16 + l16) * 64 + stv];
                O[0][nt] = MFMA16(pa0, bv_, O[0][nt]);
                O[1][nt] = MFMA16(pa1, bv_, O[1][nt]);
            }
        }
    }

    // row sums: reduce over quad lanes (each lane holds 16 of its query's keys)
    float linv[2];
    #pragma unroll
    for (int mt = 0; mt < 2; ++mt) {
        float l = lsum[mt];
        l += __shfl_xor(l, 16);
        l += __shfl_xor(l, 32);
        linv[mt] = 1.0f / l;      // sum for query (w*32 + mt*16 + l16)
    }

    // normalize + write: O rows are queries quad*4+r -> fetch inv via shuffle
    int b = bh >> 4, h = bh & (H_ - 1);
    #pragma unroll
    for (int mt = 0; mt < 2; ++mt)
        #pragma unroll
        for (int r = 0; r < 4; ++r) {
            float inv = __shfl(linv[mt], quad * 4 + r, 64);
            int q = q0 + w * 32 + mt * 16 + quad * 4 + r;
            size_t base = ((size_t)(b * S_) + q) * D_ + h * HD_;
            #pragma unroll
            for (int nt = 0; nt < 4; ++nt)
                ctx[base + nt * 16 + l16] = f2bf(O[mt][nt][r] * inv);
        }
}

extern "C" void kernel_launch(void* const* d_in, const int* in_sizes, int n_in,
                              void* d_out, int out_size, void* d_ws, size_t ws_size,
                              hipStream_t stream) {
    const float* x  = (const float*)d_in[0];
    const float* Wq = (const float*)d_in[1];
    const float* bq = (const float*)d_in[2];
    const float* Wk = (const float*)d_in[3];
    const float* bk = (const float*)d_in[4];
    const float* Wv = (const float*)d_in[5];
    const float* bv = (const float*)d_in[6];
    const float* Wo = (const float*)d_in[7];
    const float* bo = (const float*)d_in[8];

    unsigned short* xb  = (unsigned short*)d_ws;
    unsigned short* wb  = xb + (size_t)M_ * D_;
    unsigned short* Qb  = wb + (size_t)4 * D_ * D_;
    unsigned short* Kb  = Qb + (size_t)M_ * D_;
    unsigned short* VTb = Kb + (size_t)M_ * D_;
    unsigned short* ctb = VTb + (size_t)M_ * D_;

    int cvt_blocks = (M_ * D_ + 4 * D_ * D_) / 1024;
    cvt_all<<<cvt_blocks, 256, 0, stream>>>(x, Wq, Wk, Wv, Wo, xb, wb);

    qkv_gemm<<<dim3(D_ / 128, M_ / 128, 3), 512, 0, stream>>>(
        xb, wb, wb + (size_t)D_ * D_, wb + (size_t)2 * D_ * D_,
        bq, bk, bv, Qb, Kb, VTb);

    attn_mfma<<<dim3(S_ / 128, B_ * H_), 256, 0, stream>>>(Qb, Kb, VTb, ctb);

    out_gemm<<<dim3(D_ / 128, M_ / 128), 512, 0, stream>>>(
        ctb, wb + (size_t)3 * D_ * D_, bo, (float*)d_out);
}